// Round 6
// baseline (302.412 us; speedup 1.0000x reference)
//
#include <hip/hip_runtime.h>
#include <stdint.h>

#define GM 4096
#define GN 4096
#define GK 4096
#define QW (GN/8)   /* 512 packed words per k-row */
#define KT (GK/32)  /* 128 k-tiles */

typedef __attribute__((ext_vector_type(8))) short bf16x8;
typedef __attribute__((ext_vector_type(4))) float f32x4;

static __device__ __forceinline__ uint32_t bf16pack_rn(float hi, float lo) {
  // round-half-up to bf16 (removes truncation bias; inputs finite)
  uint32_t h = __float_as_uint(hi) + 0x8000u;
  uint32_t l = __float_as_uint(lo) + 0x8000u;
  return __builtin_amdgcn_perm(h, l, 0x07060302u);
}

// Fragment-major layout for both operands (rows = m for A, n for W^T):
//   tile = 16 rows x 32 k; chunk l (l=0..63) = X[rt*16 + (l&15)][kt*32 + (l>>4)*8 .. +8]
//   addr (ushorts) = ((rt*KT + kt)*64 + l) * 8
// A wave's fragment load is lane l -> chunk l: one fully-coalesced 1KB dwordx4.

// ---------- Kernel 1: A fp32 -> bf16, shuffled to fragment-major ----------
__global__ void __launch_bounds__(256) a_shuffle(const float* __restrict__ A,
                                                 ushort* __restrict__ out) {
  __shared__ __align__(16) ushort T[16 * 264];   // 16 rows x 256 k, stride 264 (pad)
  const int tid = threadIdx.x;
  const int kc  = blockIdx.x;        // 0..15 (256-k chunk)
  const int rt  = blockIdx.y;        // 0..255 (16-row tile)
  const int row = tid >> 4;          // 0..15
  const int kl  = (tid & 15) * 4;

  #pragma unroll
  for (int c = 0; c < 4; ++c) {
    float4 v = *(const float4*)(A + (size_t)(rt * 16 + row) * GK + kc * 256 + c * 64 + kl);
    *(uint2*)(&T[row * 264 + c * 64 + kl]) =
        make_uint2(bf16pack_rn(v.y, v.x), bf16pack_rn(v.w, v.z));
  }
  __syncthreads();
  const int l = tid & 63;
  #pragma unroll
  for (int c = 0; c < 2; ++c) {
    int tl = c * 4 + (tid >> 6);                 // 0..7 local k-tile
    uint4 v = *(const uint4*)(&T[(l & 15) * 264 + tl * 32 + (l >> 4) * 8]);
    *(uint4*)(&out[(((size_t)rt * KT + kc * 8 + tl) * 64 + l) * 8]) = v;
  }
}

// ---- Kernel 2: int4 dequant -> bf16 W^T, shuffled to fragment-major ----
__global__ void __launch_bounds__(256) w_dequant(const float* __restrict__ S,
                                                 const uint32_t* __restrict__ Q,
                                                 ushort* __restrict__ out) {
  __shared__ __align__(16) ushort T[128 * 64];   // 16 KB, rows = n, swizzled k
  const int tid = threadIdx.x;
  const int n0  = blockIdx.x * 128;
  const int k0  = blockIdx.y * 64;
  const int g   = k0 >> 7;                       // scale group (uniform)

  #pragma unroll
  for (int c = 0; c < 2; ++c) {
    int idx = c * 256 + tid;
    int w   = idx & 15;                          // word col 0..15
    int k   = (idx >> 4) * 2;                    // even k 0..62
    uint32_t q0 = Q[(size_t)(k0 + k)     * QW + (n0 >> 3) + w];
    uint32_t q1 = Q[(size_t)(k0 + k + 1) * QW + (n0 >> 3) + w];
    const float* sp = S + (size_t)g * GN + n0 + w * 8;
    float4 sa = *(const float4*)sp, sb = *(const float4*)(sp + 4);
    float sv[8] = {sa.x, sa.y, sa.z, sa.w, sb.x, sb.y, sb.z, sb.w};
    const int swz = 8 * (w & 7);
    #pragma unroll
    for (int j = 0; j < 8; ++j) {
      float fa = (float)((q0 >> (4 * j)) & 0xFu);    // exact int->f32
      float fb = (float)((q1 >> (4 * j)) & 0xFu);
      float wa = fmaf(fa, sv[j], -8.0f * sv[j]);     // (nib-8)*s, 1 rounding
      float wb = fmaf(fb, sv[j], -8.0f * sv[j]);
      int n = w * 8 + j;
      *(uint32_t*)(&T[n * 64 + (k ^ swz)]) = bf16pack_rn(wb, wa);
    }
  }
  __syncthreads();
  const int l = tid & 63;
  #pragma unroll
  for (int c = 0; c < 4; ++c) {
    int id  = c * 4 + (tid >> 6);                // 0..15 output tiles
    int ntl = id >> 1, ktl = id & 1;
    int n   = ntl * 16 + (l & 15);
    int ko8 = ktl * 4 + (l >> 4);                // logical k-oct 0..7
    uint4 v = *(const uint4*)(&T[n * 64 + ((ko8 ^ ((n >> 3) & 7)) * 8)]);
    *(uint4*)(&out[((((size_t)(n0 >> 4) + ntl) * KT + (k0 >> 5) + ktl) * 64 + l) * 8]) = v;
  }
}

// ---------- Kernel 3: bf16 GEMM, NO LDS / NO BARRIERS ----------
// 128x128 block, 4 waves 2x2 (64x64 each), 4x4 16x16x32 MFMA.
// Operands stream from fragment-major global layout: per k-tile each wave does
// 8 coalesced 1KB loads + 16 MFMA; compiler is free to interleave with
// fine-grained vmcnt (no barrier drain). Wave pairs share fragments via L1.
__global__ void __launch_bounds__(256, 4) gemm_frag(const ushort* __restrict__ Ash,
                                                    const ushort* __restrict__ Bsh,
                                                    float* __restrict__ C) {
  const int tid  = threadIdx.x;
  const int m0   = blockIdx.y * 128;
  const int n0   = blockIdx.x * 128;
  const int ln   = tid & 63;
  const int wid  = tid >> 6;
  const int wm   = (wid >> 1) * 64;
  const int wn   = (wid & 1) * 64;
  const int col  = ln & 15;
  const int quad = ln >> 4;

  // block-uniform bases (SGPR); wave/lane part in 32-bit voffsets (loop-invariant)
  const ushort* pA = Ash + (size_t)(m0 >> 4) * KT * 64 * 8;
  const ushort* pB = Bsh + (size_t)(n0 >> 4) * KT * 64 * 8;
  int voffA[4], voffB[4];
  #pragma unroll
  for (int t = 0; t < 4; ++t) {
    voffA[t] = (((wm >> 4) + t) * KT * 64 + ln) * 8;
    voffB[t] = (((wn >> 4) + t) * KT * 64 + ln) * 8;
  }

  f32x4 acc[4][4];
  #pragma unroll
  for (int i = 0; i < 4; ++i)
    #pragma unroll
    for (int j = 0; j < 4; ++j)
      acc[i][j] = (f32x4){0.f, 0.f, 0.f, 0.f};

  for (int kt = 0; kt < KT; kt += 2) {           // base steps by 2 tiles
    #pragma unroll
    for (int kk = 0; kk < 2; ++kk) {
      bf16x8 af[4], bfr[4];
      #pragma unroll
      for (int t = 0; t < 4; ++t) {
        af[t]  = *(const bf16x8*)(pA + voffA[t] + kk * 512);
        bfr[t] = *(const bf16x8*)(pB + voffB[t] + kk * 512);
      }
      #pragma unroll
      for (int mt = 0; mt < 4; ++mt)
        #pragma unroll
        for (int nt = 0; nt < 4; ++nt)
          acc[mt][nt] = __builtin_amdgcn_mfma_f32_16x16x32_bf16(
                            af[mt], bfr[nt], acc[mt][nt], 0, 0, 0);
    }
    pA += 1024;                                  // 2 tiles * 512 ushorts
    pB += 1024;
  }

  // epilogue: C/D layout col=lane&15, row=quad*4+reg (m89)
  #pragma unroll
  for (int mt = 0; mt < 4; ++mt)
    #pragma unroll
    for (int nt = 0; nt < 4; ++nt)
      #pragma unroll
      for (int r = 0; r < 4; ++r)
        C[(size_t)(m0 + wm + mt * 16 + quad * 4 + r) * GN
          + n0 + wn + nt * 16 + col] = acc[mt][nt][r];
}

// ---------------- Fallback: fused dequant GEMM (round-2 kernel) ----------------
#define BM 128
#define BN 128
#define BK 32

__global__ void __launch_bounds__(256) w4a32_gemm(
    const float* __restrict__ A,
    const float* __restrict__ S,
    const uint32_t* __restrict__ Q,
    float* __restrict__ C)
{
  __shared__ __align__(16) ushort As[BM*BK];
  __shared__ __align__(16) ushort Bs[BN*BK];

  const int tid  = threadIdx.x;
  const int m0   = blockIdx.y*BM;
  const int n0   = blockIdx.x*BN;
  const int wcol  = tid & 15;
  const int kpair = tid >> 4;
  const int ln   = tid & 63;
  const int wid  = tid >> 6;
  const int wm   = (wid >> 1) * 64;
  const int wn   = (wid & 1) * 64;
  const int col  = ln & 15;
  const int quad = ln >> 4;

  f32x4 acc[4][4];
  #pragma unroll
  for (int i=0;i<4;++i)
    #pragma unroll
    for (int j=0;j<4;++j)
      acc[i][j] = (f32x4){0.f,0.f,0.f,0.f};

  float sv[8], cv[8];
  float4 spf0, spf1;

  const float*    Abase = A + (size_t)m0 * GK;
  const uint32_t* Qbase = Q + (size_t)(n0>>3) + wcol;

  {
    const float* sp = S + n0 + wcol*8;
    spf0 = *(const float4*)sp;
    spf1 = *(const float4*)(sp + 4);
  }

  float4 a4[4];
  uint32_t wqa, wqb;
  #pragma unroll
  for (int i=0;i<4;++i) {
    int f = tid + i*256;
    a4[i] = *(const float4*)(Abase + (size_t)(f>>3)*GK + ((f&7)*4));
  }
  wqa = Qbase[(size_t)(2*kpair)   * QW];
  wqb = Qbase[(size_t)(2*kpair+1) * QW];

  for (int k0 = 0; k0 < GK; k0 += BK) {
    if ((k0 & 127) == 0) {
      sv[0]=spf0.x; sv[1]=spf0.y; sv[2]=spf0.z; sv[3]=spf0.w;
      sv[4]=spf1.x; sv[5]=spf1.y; sv[6]=spf1.z; sv[7]=spf1.w;
      #pragma unroll
      for (int j=0;j<8;++j) cv[j] = -8.0f * sv[j];
    }

    #pragma unroll
    for (int i=0;i<4;++i) {
      int f = tid + i*256;
      int row = f>>3, c4 = f&7;
      *(uint2*)(&As[row*BK + c4*4]) =
        make_uint2(bf16pack_rn(a4[i].y, a4[i].x), bf16pack_rn(a4[i].w, a4[i].z));
    }

    {
      const int kk = (2*kpair) ^ (8*(wcol&3));
      #pragma unroll
      for (int j=0;j<8;++j) {
        float fa = (float)((wqa >> (4*j)) & 0xFu);
        float fb = (float)((wqb >> (4*j)) & 0xFu);
        float wa = fmaf(fa, sv[j], cv[j]);
        float wb = fmaf(fb, sv[j], cv[j]);
        int n = wcol*8 + j;
        *(uint32_t*)(&Bs[n*BK + kk]) = bf16pack_rn(wb, wa);
      }
    }

    int kn = k0 + BK; if (kn >= GK) kn = 0;
    if ((kn & 127) == 0) {
      const float* sp = S + (size_t)(kn>>7)*GN + n0 + wcol*8;
      spf0 = *(const float4*)sp;
      spf1 = *(const float4*)(sp + 4);
    }
    #pragma unroll
    for (int i=0;i<4;++i) {
      int f = tid + i*256;
      a4[i] = *(const float4*)(Abase + (size_t)(f>>3)*GK + kn + ((f&7)*4));
    }
    wqa = Qbase[(size_t)(kn + 2*kpair)   * QW];
    wqb = Qbase[(size_t)(kn + 2*kpair+1) * QW];

    __syncthreads();

    bf16x8 af[4], bfr[4];
    #pragma unroll
    for (int t=0;t<4;++t) {
      af[t] = *(const bf16x8*)(&As[(wm + t*16 + col)*BK + quad*8]);
      int n = wn + t*16 + col;
      int kk = (quad*8) ^ (8*((n>>3)&3));
      bfr[t] = *(const bf16x8*)(&Bs[n*BK + kk]);
    }
    #pragma unroll
    for (int mt=0;mt<4;++mt)
      #pragma unroll
      for (int nt=0;nt<4;++nt)
        acc[mt][nt] = __builtin_amdgcn_mfma_f32_16x16x32_bf16(
                          af[mt], bfr[nt], acc[mt][nt], 0, 0, 0);

    __syncthreads();
  }

  #pragma unroll
  for (int mt=0;mt<4;++mt)
    #pragma unroll
    for (int nt=0;nt<4;++nt)
      #pragma unroll
      for (int r=0;r<4;++r)
        C[(size_t)(m0 + wm + mt*16 + quad*4 + r)*GN + n0 + wn + nt*16 + col]
          = acc[mt][nt][r];
}

extern "C" void kernel_launch(void* const* d_in, const int* in_sizes, int n_in,
                              void* d_out, int out_size, void* d_ws, size_t ws_size,
                              hipStream_t stream) {
  const float*    A = (const float*)d_in[0];
  const float*    S = (const float*)d_in[1];
  const uint32_t* Q = (const uint32_t*)d_in[2];
  float*          C = (float*)d_out;

  const size_t need = (size_t)GM * GK * 2 + (size_t)GN * GK * 2;  // 64 MB
  if (ws_size >= need) {
    ushort* Ash = (ushort*)d_ws;                       // frag-major A
    ushort* Bsh = (ushort*)d_ws + (size_t)GM * GK;     // frag-major W^T
    a_shuffle<<<dim3(16, 256), dim3(256), 0, stream>>>(A, Ash);
    w_dequant<<<dim3(GN / 128, GK / 64), dim3(256), 0, stream>>>(S, Q, Bsh);
    gemm_frag<<<dim3(GN / 128, GM / 128), dim3(256), 0, stream>>>(Ash, Bsh, C);
  } else {
    w4a32_gemm<<<dim3(GN / BN, GM / BM), dim3(256), 0, stream>>>(A, S, Q, C);
  }
}

// Round 7
// 276.610 us; speedup vs baseline: 1.0933x; 1.0933x over previous
//
#include <hip/hip_runtime.h>
#include <stdint.h>

#define GM 4096
#define GN 4096
#define GK 4096
#define QW (GN/8)   /* 512 packed words per k-row */

typedef __attribute__((ext_vector_type(8))) short bf16x8;
typedef __attribute__((ext_vector_type(4))) float f32x4;

#define AS1 __attribute__((address_space(1)))
#define AS3 __attribute__((address_space(3)))

static __device__ __forceinline__ void glds16(const void* g, void* l) {
  __builtin_amdgcn_global_load_lds((const AS1 uint32_t*)g, (AS3 uint32_t*)l, 16, 0, 0);
}

static __device__ __forceinline__ uint32_t bf16pack_rn(float hi, float lo) {
  // round-half-up to bf16 (removes truncation bias; inputs finite)
  uint32_t h = __float_as_uint(hi) + 0x8000u;
  uint32_t l = __float_as_uint(lo) + 0x8000u;
  return __builtin_amdgcn_perm(h, l, 0x07060302u);
}

// ---------------- Kernel 1: A fp32 -> bf16 (streaming, RN) ----------------
__global__ void __launch_bounds__(256) a_to_bf16(const float* __restrict__ A,
                                                 ushort* __restrict__ Ab) {
  size_t t = (size_t)blockIdx.x * 256 + threadIdx.x;
  const float4* p = (const float4*)(A + t * 8);
  float4 x = p[0], y = p[1];
  uint4 o;
  o.x = bf16pack_rn(x.y, x.x);
  o.y = bf16pack_rn(x.w, x.z);
  o.z = bf16pack_rn(y.y, y.x);
  o.w = bf16pack_rn(y.w, y.z);
  *(uint4*)(Ab + t * 8) = o;
}

// ------- Kernel 2: int4 dequant -> bf16 W^T [N][K] (LDS transpose, RN) -------
__global__ void __launch_bounds__(256) w_dequant(const float* __restrict__ S,
                                                 const uint32_t* __restrict__ Q,
                                                 ushort* __restrict__ Wt) {
  __shared__ __align__(16) ushort T[128 * 64];   // 16 KB
  const int tid = threadIdx.x;
  const int n0  = blockIdx.x * 128;
  const int k0  = blockIdx.y * 64;
  const int g   = k0 >> 7;                       // group (uniform: 64 | 128)

  #pragma unroll
  for (int c = 0; c < 2; ++c) {
    int idx = c * 256 + tid;
    int w   = idx & 15;                          // word col 0..15
    int k   = (idx >> 4) * 2;                    // even k 0..62
    uint32_t q0 = Q[(size_t)(k0 + k)     * QW + (n0 >> 3) + w];
    uint32_t q1 = Q[(size_t)(k0 + k + 1) * QW + (n0 >> 3) + w];
    const float* sp = S + (size_t)g * GN + n0 + w * 8;
    float4 sa = *(const float4*)sp, sb = *(const float4*)(sp + 4);
    float sv[8] = {sa.x, sa.y, sa.z, sa.w, sb.x, sb.y, sb.z, sb.w};
    const int swz = 8 * (w & 7);
    #pragma unroll
    for (int j = 0; j < 8; ++j) {
      float fa = (float)((q0 >> (4 * j)) & 0xFu);    // exact int->f32
      float fb = (float)((q1 >> (4 * j)) & 0xFu);
      float wa = fmaf(fa, sv[j], -8.0f * sv[j]);     // (nib-8)*s, 1 rounding
      float wb = fmaf(fb, sv[j], -8.0f * sv[j]);
      int n = w * 8 + j;
      *(uint32_t*)(&T[n * 64 + (k ^ swz)]) = bf16pack_rn(wb, wa);
    }
  }
  __syncthreads();
  #pragma unroll
  for (int c = 0; c < 4; ++c) {
    int idx = c * 256 + tid;
    int n = idx >> 3, ko = idx & 7;
    int swz = (n >> 3) & 7;
    uint4 v = *(const uint4*)(&T[n * 64 + 8 * (ko ^ swz)]);
    *(uint4*)(&Wt[(size_t)(n0 + n) * GK + k0 + ko * 8]) = v;
  }
}

// ---------------- Kernel 3: bf16 GEMM, K32 double-buffered ----------------
// 128x128 block, K32 tiles double-buffered (8KB/op/buf, 32KB total -> 4 blk/CU),
// ONE __syncthreads per step; glds for tile k+1 issued after the barrier and
// in flight across the whole compute phase -> next barrier's vmcnt(0) drain
// finds it complete (removes round-5's ~900cyc/step stall).
// LDS layout: line L (128B) holds rows (L, L+64) as chunks 0-3 / 4-7; chunk
// slot h at line L stores logical chunk h^(L&7) (the round-4/5 verified
// zero-conflict pattern), implemented by permuting the GLOBAL source per
// thread (glds dest must be linear lane*16).
__global__ void __launch_bounds__(256, 4) gemm_bf16(const ushort* __restrict__ Ab,
                                                    const ushort* __restrict__ Wt,
                                                    float* __restrict__ C) {
  __shared__ __align__(16) ushort As[2][64 * 64];  // 2 x 8 KB
  __shared__ __align__(16) ushort Bs[2][64 * 64];  // 2 x 8 KB

  const int tid  = threadIdx.x;
  const int m0   = blockIdx.y * 128;
  const int n0   = blockIdx.x * 128;
  const int ln   = tid & 63;
  const int wid  = tid >> 6;
  const int wm   = (wid >> 1) * 64;
  const int wn   = (wid & 1) * 64;
  const int col  = ln & 15;
  const int quad = ln >> 4;

  // staging map: thread t -> line L0 = t>>3 (round1: +32), slot h = t&7
  // slot h at line L holds logical chunk c = h ^ (L&7)  ((L+32)&7 == L&7)
  const int L0 = tid >> 3;
  const int h  = tid & 7;
  const int c  = h ^ (L0 & 7);
  const int r0 = L0 + (c >> 2) * 64;        // source row, round 0
  const int r1 = L0 + 32 + (c >> 2) * 64;   // source row, round 1
  const int sk = (c & 3) * 8;               // source k-offset (ushorts)

  const ushort* Asrc0 = Ab + (size_t)(m0 + r0) * GK + sk;
  const ushort* Asrc1 = Ab + (size_t)(m0 + r1) * GK + sk;
  const ushort* Bsrc0 = Wt + (size_t)(n0 + r0) * GK + sk;
  const ushort* Bsrc1 = Wt + (size_t)(n0 + r1) * GK + sk;

  f32x4 acc[4][4];
  #pragma unroll
  for (int i = 0; i < 4; ++i)
    #pragma unroll
    for (int j = 0; j < 4; ++j)
      acc[i][j] = (f32x4){0.f, 0.f, 0.f, 0.f};

  // compute-side swizzled chunk indices (t-independent: (t*16+col)&7 == col&7)
  const int cpa = ((wm >> 6) * 4 + quad) ^ (col & 7);
  const int cpb = ((wn >> 6) * 4 + quad) ^ (col & 7);

#define STAGE(kt, b)                                            \
  do {                                                          \
    int koff = (kt) * 32;                                       \
    glds16(Asrc0 + koff, &As[b][tid * 8]);                      \
    glds16(Asrc1 + koff, &As[b][2048 + tid * 8]);               \
    glds16(Bsrc0 + koff, &Bs[b][tid * 8]);                      \
    glds16(Bsrc1 + koff, &Bs[b][2048 + tid * 8]);               \
  } while (0)

#define COMPUTE(b)                                                        \
  do {                                                                    \
    bf16x8 af[4], bfr[4];                                                 \
    _Pragma("unroll")                                                     \
    for (int t = 0; t < 4; ++t) {                                         \
      af[t]  = *(const bf16x8*)(&As[b][(t * 16 + col) * 64 + cpa * 8]);   \
      bfr[t] = *(const bf16x8*)(&Bs[b][(t * 16 + col) * 64 + cpb * 8]);   \
    }                                                                     \
    _Pragma("unroll")                                                     \
    for (int mt = 0; mt < 4; ++mt)                                        \
      _Pragma("unroll")                                                   \
      for (int nt = 0; nt < 4; ++nt)                                      \
        acc[mt][nt] = __builtin_amdgcn_mfma_f32_16x16x32_bf16(            \
                          af[mt], bfr[nt], acc[mt][nt], 0, 0, 0);         \
  } while (0)

  STAGE(0, 0);
  for (int s = 0; s < 128; s += 2) {
    __syncthreads();               // tile s ready in buf0; prior buf1 reads done
    STAGE(s + 1, 1);               // in flight across compute
    COMPUTE(0);
    __syncthreads();               // tile s+1 ready in buf1; buf0 reads done
    STAGE((s + 2) & 127, 0);       // final iter restages tile 0 (harmless)
    COMPUTE(1);
  }
#undef STAGE
#undef COMPUTE

  // epilogue: C/D layout col=lane&15, row=quad*4+reg (m89)
  #pragma unroll
  for (int mt = 0; mt < 4; ++mt)
    #pragma unroll
    for (int nt = 0; nt < 4; ++nt)
      #pragma unroll
      for (int r = 0; r < 4; ++r)
        C[(size_t)(m0 + wm + mt * 16 + quad * 4 + r) * GN
          + n0 + wn + nt * 16 + col] = acc[mt][nt][r];
}

// ---------------- Fallback: fused dequant GEMM (round-2 kernel) ----------------
#define BM 128
#define BN 128
#define BK 32

__global__ void __launch_bounds__(256) w4a32_gemm(
    const float* __restrict__ A,
    const float* __restrict__ S,
    const uint32_t* __restrict__ Q,
    float* __restrict__ C)
{
  __shared__ __align__(16) ushort As[BM*BK];
  __shared__ __align__(16) ushort Bs[BN*BK];

  const int tid  = threadIdx.x;
  const int m0   = blockIdx.y*BM;
  const int n0   = blockIdx.x*BN;
  const int wcol  = tid & 15;
  const int kpair = tid >> 4;
  const int ln   = tid & 63;
  const int wid  = tid >> 6;
  const int wm   = (wid >> 1) * 64;
  const int wn   = (wid & 1) * 64;
  const int col  = ln & 15;
  const int quad = ln >> 4;

  f32x4 acc[4][4];
  #pragma unroll
  for (int i=0;i<4;++i)
    #pragma unroll
    for (int j=0;j<4;++j)
      acc[i][j] = (f32x4){0.f,0.f,0.f,0.f};

  float sv[8], cv[8];
  float4 spf0, spf1;

  const float*    Abase = A + (size_t)m0 * GK;
  const uint32_t* Qbase = Q + (size_t)(n0>>3) + wcol;

  {
    const float* sp = S + n0 + wcol*8;
    spf0 = *(const float4*)sp;
    spf1 = *(const float4*)(sp + 4);
  }

  float4 a4[4];
  uint32_t wqa, wqb;
  #pragma unroll
  for (int i=0;i<4;++i) {
    int f = tid + i*256;
    a4[i] = *(const float4*)(Abase + (size_t)(f>>3)*GK + ((f&7)*4));
  }
  wqa = Qbase[(size_t)(2*kpair)   * QW];
  wqb = Qbase[(size_t)(2*kpair+1) * QW];

  for (int k0 = 0; k0 < GK; k0 += BK) {
    if ((k0 & 127) == 0) {
      sv[0]=spf0.x; sv[1]=spf0.y; sv[2]=spf0.z; sv[3]=spf0.w;
      sv[4]=spf1.x; sv[5]=spf1.y; sv[6]=spf1.z; sv[7]=spf1.w;
      #pragma unroll
      for (int j=0;j<8;++j) cv[j] = -8.0f * sv[j];
    }

    #pragma unroll
    for (int i=0;i<4;++i) {
      int f = tid + i*256;
      int row = f>>3, c4 = f&7;
      *(uint2*)(&As[row*BK + c4*4]) =
        make_uint2(bf16pack_rn(a4[i].y, a4[i].x), bf16pack_rn(a4[i].w, a4[i].z));
    }

    {
      const int kk = (2*kpair) ^ (8*(wcol&3));
      #pragma unroll
      for (int j=0;j<8;++j) {
        float fa = (float)((wqa >> (4*j)) & 0xFu);
        float fb = (float)((wqb >> (4*j)) & 0xFu);
        float wa = fmaf(fa, sv[j], cv[j]);
        float wb = fmaf(fb, sv[j], cv[j]);
        int n = wcol*8 + j;
        *(uint32_t*)(&Bs[n*BK + kk]) = bf16pack_rn(wb, wa);
      }
    }

    int kn = k0 + BK; if (kn >= GK) kn = 0;
    if ((kn & 127) == 0) {
      const float* sp = S + (size_t)(kn>>7)*GN + n0 + wcol*8;
      spf0 = *(const float4*)sp;
      spf1 = *(const float4*)(sp + 4);
    }
    #pragma unroll
    for (int i=0;i<4;++i) {
      int f = tid + i*256;
      a4[i] = *(const float4*)(Abase + (size_t)(f>>3)*GK + kn + ((f&7)*4));
    }
    wqa = Qbase[(size_t)(kn + 2*kpair)   * QW];
    wqb = Qbase[(size_t)(kn + 2*kpair+1) * QW];

    __syncthreads();

    bf16x8 af[4], bfr[4];
    #pragma unroll
    for (int t=0;t<4;++t) {
      af[t] = *(const bf16x8*)(&As[(wm + t*16 + col)*BK + quad*8]);
      int n = wn + t*16 + col;
      int kk = (quad*8) ^ (8*((n>>3)&3));
      bfr[t] = *(const bf16x8*)(&Bs[n*BK + kk]);
    }
    #pragma unroll
    for (int mt=0;mt<4;++mt)
      #pragma unroll
      for (int nt=0;nt<4;++nt)
        acc[mt][nt] = __builtin_amdgcn_mfma_f32_16x16x32_bf16(
                          af[mt], bfr[nt], acc[mt][nt], 0, 0, 0);

    __syncthreads();
  }

  #pragma unroll
  for (int mt=0;mt<4;++mt)
    #pragma unroll
    for (int nt=0;nt<4;++nt)
      #pragma unroll
      for (int r=0;r<4;++r)
        C[(size_t)(m0 + wm + mt*16 + quad*4 + r)*GN + n0 + wn + nt*16 + col]
          = acc[mt][nt][r];
}

extern "C" void kernel_launch(void* const* d_in, const int* in_sizes, int n_in,
                              void* d_out, int out_size, void* d_ws, size_t ws_size,
                              hipStream_t stream) {
  const float*    A = (const float*)d_in[0];
  const float*    S = (const float*)d_in[1];
  const uint32_t* Q = (const uint32_t*)d_in[2];
  float*          C = (float*)d_out;

  const size_t need = (size_t)GM * GK * 2 + (size_t)GN * GK * 2;  // 64 MB
  if (ws_size >= need) {
    ushort* Abf = (ushort*)d_ws;                       // [M][K] bf16
    ushort* Wt  = (ushort*)d_ws + (size_t)GM * GK;     // [N][K] bf16 (W^T)
    a_to_bf16<<<dim3(GM * GK / (8 * 256)), dim3(256), 0, stream>>>(A, Abf);
    w_dequant<<<dim3(GN / 128, GK / 64), dim3(256), 0, stream>>>(S, Q, Wt);
    gemm_bf16<<<dim3(GN / 128, GM / 128), dim3(256), 0, stream>>>(Abf, Wt, C);
  } else {
    w4a32_gemm<<<dim3(GN / BN, GM / BM), dim3(256), 0, stream>>>(A, S, Q, C);
  }
}

// Round 8
// 232.833 us; speedup vs baseline: 1.2988x; 1.1880x over previous
//
#include <hip/hip_runtime.h>
#include <stdint.h>

#define GM 4096
#define GN 4096
#define GK 4096
#define QW (GN/8)   /* 512 packed words per k-row */

typedef __attribute__((ext_vector_type(4))) int   i32x4;
typedef __attribute__((ext_vector_type(8))) short bf16x8;
typedef __attribute__((ext_vector_type(4))) float f32x4;

#define AS1 __attribute__((address_space(1)))
#define AS3 __attribute__((address_space(3)))

static __device__ __forceinline__ void glds16(const void* g, void* l) {
  __builtin_amdgcn_global_load_lds((const AS1 uint32_t*)g, (AS3 uint32_t*)l, 16, 0, 0);
}

static __device__ __forceinline__ uint32_t bf16pack_rn(float hi, float lo) {
  uint32_t h = __float_as_uint(hi) + 0x8000u;
  uint32_t l = __float_as_uint(lo) + 0x8000u;
  return __builtin_amdgcn_perm(h, l, 0x07060302u);
}

// ---------- Kernel 1: A fp32 -> i8 per-row symmetric quant ----------
__global__ void __launch_bounds__(256) a_quant(const float* __restrict__ A,
                                               int8_t* __restrict__ Ai,
                                               float* __restrict__ ascale) {
  __shared__ float red[256];
  const int row = blockIdx.x, t = threadIdx.x;
  const float* src = A + (size_t)row * GK;
  float4 v[4];
  float m = 0.f;
  #pragma unroll
  for (int c = 0; c < 4; ++c) {
    v[c] = *(const float4*)(src + c * 1024 + t * 4);
    m = fmaxf(m, fmaxf(fmaxf(fabsf(v[c].x), fabsf(v[c].y)),
                       fmaxf(fabsf(v[c].z), fabsf(v[c].w))));
  }
  red[t] = m; __syncthreads();
  for (int s = 128; s > 0; s >>= 1) {
    if (t < s) red[t] = fmaxf(red[t], red[t + s]);
    __syncthreads();
  }
  const float rmax = fmaxf(red[0], 1e-20f);
  const float inv  = 127.0f / rmax;
  #pragma unroll
  for (int c = 0; c < 4; ++c) {
    int b0 = (int)__builtin_rintf(v[c].x * inv);
    int b1 = (int)__builtin_rintf(v[c].y * inv);
    int b2 = (int)__builtin_rintf(v[c].z * inv);
    int b3 = (int)__builtin_rintf(v[c].w * inv);
    uint32_t b = ((uint32_t)b0 & 255u) | (((uint32_t)b1 & 255u) << 8) |
                 (((uint32_t)b2 & 255u) << 16) | (((uint32_t)b3 & 255u) << 24);
    *(uint32_t*)(Ai + (size_t)row * GK + c * 1024 + t * 4) = b;
  }
  if (t == 0) ascale[row] = rmax * (1.0f / 127.0f);
}

// ---------- Kernel 1b: per-column weight scale = 8*max_g s / 127 ----------
__global__ void __launch_bounds__(256) w_scale(const float* __restrict__ S,
                                               float* __restrict__ wscale,
                                               float* __restrict__ winv) {
  const int n = blockIdx.x * 256 + threadIdx.x;
  float m = 0.f;
  #pragma unroll 8
  for (int g = 0; g < 32; ++g) m = fmaxf(m, S[(size_t)g * GN + n]);
  wscale[n] = m * (8.0f / 127.0f);
  winv[n]   = 127.0f / (8.0f * m);
}

// ---------- Kernel 2: int4 -> i8 W^T [N][K], scales folded in ----------
// W_i8[k][n] = round((nib-8) * s_g[n] * winv[n]); |.| <= 127 by construction.
// Thread -> one (n, 16k) 16B output chunk; writes coalesced (16 lanes = 256B).
__global__ void __launch_bounds__(256) w_quant(const float* __restrict__ S,
                                               const uint32_t* __restrict__ Q,
                                               const float* __restrict__ winv,
                                               int8_t* __restrict__ Wt) {
  const int t  = threadIdx.x;
  const int n  = (blockIdx.x & 255) * 16 + (t >> 4);
  const int k0 = (blockIdx.x >> 8) * 256 + (t & 15) * 16;
  const int g  = k0 >> 7;                       // 16-aligned -> single group
  const float r = S[(size_t)g * GN + n] * winv[n];
  const float c = -8.0f * r;
  const int wc = n >> 3, sh = (n & 7) * 4;
  uint32_t out[4];
  #pragma unroll
  for (int i = 0; i < 4; ++i) {
    uint32_t b = 0;
    #pragma unroll
    for (int j = 0; j < 4; ++j) {
      uint32_t q = Q[(size_t)(k0 + i * 4 + j) * QW + wc];
      float nib = (float)((q >> sh) & 0xFu);
      int w = (int)__builtin_rintf(fmaf(nib, r, c));
      b |= ((uint32_t)w & 255u) << (8 * j);
    }
    out[i] = b;
  }
  *(uint4*)(Wt + (size_t)n * GK + k0) = make_uint4(out[0], out[1], out[2], out[3]);
}

// ---------- Kernel 3: i8 GEMM, round-5 structure (K64, 2-barrier) ----------
// 128x128 block, 4 waves 2x2 (64x64), 4x4 tiles of mfma_i32_16x16x64_i8
// (16 MFMA & 8 ds_read_b128 per wave per K64 — HALF the bf16 LDS traffic).
// LDS tile 128 rows x 64 k i8 (8 KB/op). Row = 64 B; 16B chunk q of row r
// stored at phys chunk q ^ ((r ^ (r>>2))&3) -> bank-uniform reads (2-way
// aliasing only = free, m136). Swizzle applied on the glds SOURCE address
// (dest is fixed lane*16). i32 acc (64 AGPR) — scales are K-invariant
// (folded into i8 W), applied in epilogue: C = ascale[m]*wscale[n]*acc.
__global__ void __launch_bounds__(256, 4) gemm_i8(const int8_t* __restrict__ Ai,
                                                  const int8_t* __restrict__ Wi,
                                                  const float* __restrict__ ascale,
                                                  const float* __restrict__ wscale,
                                                  float* __restrict__ C) {
  __shared__ __align__(16) int8_t As[128 * 64];  // 8 KB
  __shared__ __align__(16) int8_t Bs[128 * 64];  // 8 KB

  const int tid  = threadIdx.x;
  const int m0   = blockIdx.y * 128;
  const int n0   = blockIdx.x * 128;
  const int ln   = tid & 63;
  const int wid  = tid >> 6;
  const int wm   = (wid >> 1) * 64;
  const int wn   = (wid & 1) * 64;
  const int col  = ln & 15;
  const int quad = ln >> 4;

  // staging: thread t -> LDS offset t*16 (row r=t>>2, phys chunk t&3);
  // source logical chunk = (t&3) ^ sw(r), sw(r)=((t>>2)^(t>>4))&3 (same for r and r+64)
  const int swt = ((tid >> 2) ^ (tid >> 4)) & 3;
  const int qo  = ((tid & 3) ^ swt) * 16;
  const int rs  = tid >> 2;
  const int8_t* Asrc0 = Ai + (size_t)(m0 + rs) * GK + qo;
  const int8_t* Asrc1 = Ai + (size_t)(m0 + 64 + rs) * GK + qo;
  const int8_t* Bsrc0 = Wi + (size_t)(n0 + rs) * GK + qo;
  const int8_t* Bsrc1 = Wi + (size_t)(n0 + 64 + rs) * GK + qo;

  // fragment reads: row = base + t*16 + col -> sw(row) = (col ^ (col>>2))&3
  const int swl = (col ^ (col >> 2)) & 3;
  const int cq  = (quad ^ swl) * 16;

  i32x4 acc[4][4];
  #pragma unroll
  for (int i = 0; i < 4; ++i)
    #pragma unroll
    for (int j = 0; j < 4; ++j)
      acc[i][j] = (i32x4){0, 0, 0, 0};

  for (int k0 = 0; k0 < GK; k0 += 64) {
    glds16(Asrc0 + k0, &As[tid * 16]);
    glds16(Asrc1 + k0, &As[4096 + tid * 16]);
    glds16(Bsrc0 + k0, &Bs[tid * 16]);
    glds16(Bsrc1 + k0, &Bs[4096 + tid * 16]);

    __syncthreads();   // drains vmcnt; tiles ready

    i32x4 af[4], bfr[4];
    #pragma unroll
    for (int t = 0; t < 4; ++t) {
      af[t]  = *(const i32x4*)(&As[(wm + t * 16 + col) * 64 + cq]);
      bfr[t] = *(const i32x4*)(&Bs[(wn + t * 16 + col) * 64 + cq]);
    }
    #pragma unroll
    for (int mt = 0; mt < 4; ++mt)
      #pragma unroll
      for (int nt = 0; nt < 4; ++nt)
        acc[mt][nt] = __builtin_amdgcn_mfma_i32_16x16x64_i8(
                          af[mt], bfr[nt], acc[mt][nt], 0, 0, 0);

    __syncthreads();   // reads done before next stage overwrites
  }

  // epilogue: C/D col=lane&15, row=quad*4+reg (dtype-independent, m121-128)
  #pragma unroll
  for (int mt = 0; mt < 4; ++mt) {
    float4 a4 = *(const float4*)(ascale + m0 + wm + mt * 16 + quad * 4);
    const float ar[4] = {a4.x, a4.y, a4.z, a4.w};
    #pragma unroll
    for (int nt = 0; nt < 4; ++nt) {
      const float ws = wscale[n0 + wn + nt * 16 + col];
      #pragma unroll
      for (int r = 0; r < 4; ++r)
        C[(size_t)(m0 + wm + mt * 16 + quad * 4 + r) * GN
          + n0 + wn + nt * 16 + col] = (float)acc[mt][nt][r] * (ar[r] * ws);
    }
  }
}

// ---------------- Fallback: fused dequant GEMM (round-2 kernel) ----------------
#define BM 128
#define BN 128
#define BK 32

__global__ void __launch_bounds__(256) w4a32_gemm(
    const float* __restrict__ A,
    const float* __restrict__ S,
    const uint32_t* __restrict__ Q,
    float* __restrict__ C)
{
  __shared__ __align__(16) ushort As[BM*BK];
  __shared__ __align__(16) ushort Bs[BN*BK];

  const int tid  = threadIdx.x;
  const int m0   = blockIdx.y*BM;
  const int n0   = blockIdx.x*BN;
  const int wcol  = tid & 15;
  const int kpair = tid >> 4;
  const int ln   = tid & 63;
  const int wid  = tid >> 6;
  const int wm   = (wid >> 1) * 64;
  const int wn   = (wid & 1) * 64;
  const int col  = ln & 15;
  const int quad = ln >> 4;

  f32x4 acc[4][4];
  #pragma unroll
  for (int i=0;i<4;++i)
    #pragma unroll
    for (int j=0;j<4;++j)
      acc[i][j] = (f32x4){0.f,0.f,0.f,0.f};

  float sv[8], cv[8];
  float4 spf0, spf1;

  const float*    Abase = A + (size_t)m0 * GK;
  const uint32_t* Qbase = Q + (size_t)(n0>>3) + wcol;

  {
    const float* sp = S + n0 + wcol*8;
    spf0 = *(const float4*)sp;
    spf1 = *(const float4*)(sp + 4);
  }

  float4 a4[4];
  uint32_t wqa, wqb;
  #pragma unroll
  for (int i=0;i<4;++i) {
    int f = tid + i*256;
    a4[i] = *(const float4*)(Abase + (size_t)(f>>3)*GK + ((f&7)*4));
  }
  wqa = Qbase[(size_t)(2*kpair)   * QW];
  wqb = Qbase[(size_t)(2*kpair+1) * QW];

  for (int k0 = 0; k0 < GK; k0 += BK) {
    if ((k0 & 127) == 0) {
      sv[0]=spf0.x; sv[1]=spf0.y; sv[2]=spf0.z; sv[3]=spf0.w;
      sv[4]=spf1.x; sv[5]=spf1.y; sv[6]=spf1.z; sv[7]=spf1.w;
      #pragma unroll
      for (int j=0;j<8;++j) cv[j] = -8.0f * sv[j];
    }

    #pragma unroll
    for (int i=0;i<4;++i) {
      int f = tid + i*256;
      int row = f>>3, c4 = f&7;
      *(uint2*)(&As[row*BK + c4*4]) =
        make_uint2(bf16pack_rn(a4[i].y, a4[i].x), bf16pack_rn(a4[i].w, a4[i].z));
    }

    {
      const int kk = (2*kpair) ^ (8*(wcol&3));
      #pragma unroll
      for (int j=0;j<8;++j) {
        float fa = (float)((wqa >> (4*j)) & 0xFu);
        float fb = (float)((wqb >> (4*j)) & 0xFu);
        float wa = fmaf(fa, sv[j], cv[j]);
        float wb = fmaf(fb, sv[j], cv[j]);
        int n = wcol*8 + j;
        *(uint32_t*)(&Bs[n*BK + kk]) = bf16pack_rn(wb, wa);
      }
    }

    int kn = k0 + BK; if (kn >= GK) kn = 0;
    if ((kn & 127) == 0) {
      const float* sp = S + (size_t)(kn>>7)*GN + n0 + wcol*8;
      spf0 = *(const float4*)sp;
      spf1 = *(const float4*)(sp + 4);
    }
    #pragma unroll
    for (int i=0;i<4;++i) {
      int f = tid + i*256;
      a4[i] = *(const float4*)(Abase + (size_t)(f>>3)*GK + kn + ((f&7)*4));
    }
    wqa = Qbase[(size_t)(kn + 2*kpair)   * QW];
    wqb = Qbase[(size_t)(kn + 2*kpair+1) * QW];

    __syncthreads();

    bf16x8 af[4], bfr[4];
    #pragma unroll
    for (int t=0;t<4;++t) {
      af[t] = *(const bf16x8*)(&As[(wm + t*16 + col)*BK + quad*8]);
      int n = wn + t*16 + col;
      int kk = (quad*8) ^ (8*((n>>3)&3));
      bfr[t] = *(const bf16x8*)(&Bs[n*BK + kk]);
    }
    #pragma unroll
    for (int mt=0;mt<4;++mt)
      #pragma unroll
      for (int nt=0;nt<4;++nt)
        acc[mt][nt] = __builtin_amdgcn_mfma_f32_16x16x32_bf16(
                          af[mt], bfr[nt], acc[mt][nt], 0, 0, 0);

    __syncthreads();
  }

  #pragma unroll
  for (int mt=0;mt<4;++mt)
    #pragma unroll
    for (int nt=0;nt<4;++nt)
      #pragma unroll
      for (int r=0;r<4;++r)
        C[(size_t)(m0 + wm + mt*16 + quad*4 + r)*GN + n0 + wn + nt*16 + col]
          = acc[mt][nt][r];
}

extern "C" void kernel_launch(void* const* d_in, const int* in_sizes, int n_in,
                              void* d_out, int out_size, void* d_ws, size_t ws_size,
                              hipStream_t stream) {
  const float*    A = (const float*)d_in[0];
  const float*    S = (const float*)d_in[1];
  const uint32_t* Q = (const uint32_t*)d_in[2];
  float*          C = (float*)d_out;

  const size_t need = (size_t)GM * GK + (size_t)GN * GK + 3 * 4096 * 4 + 4096;
  if (ws_size >= need) {
    int8_t* Ai  = (int8_t*)d_ws;                          // [M][K] i8, 16 MB
    int8_t* Wt  = Ai + (size_t)GM * GK;                   // [N][K] i8, 16 MB
    float* ascale = (float*)(Wt + (size_t)GN * GK);       // 4096 f32
    float* wscale = ascale + 4096;
    float* winv   = wscale + 4096;
    a_quant<<<dim3(GM), dim3(256), 0, stream>>>(A, Ai, ascale);
    w_scale<<<dim3(GN / 256), dim3(256), 0, stream>>>(S, wscale, winv);
    w_quant<<<dim3(4096), dim3(256), 0, stream>>>(S, Q, winv, Wt);
    gemm_i8<<<dim3(GN / 128, GM / 128), dim3(256), 0, stream>>>(Ai, Wt, ascale, wscale, C);
  } else {
    w4a32_gemm<<<dim3(GN / BN, GM / BM), dim3(256), 0, stream>>>(A, S, Q, C);
  }
}

// Round 9
// 217.243 us; speedup vs baseline: 1.3920x; 1.0718x over previous
//
#include <hip/hip_runtime.h>
#include <stdint.h>

#define GM 4096
#define GN 4096
#define GK 4096
#define QW (GN/8)   /* 512 packed words per k-row */

typedef __attribute__((ext_vector_type(4))) int   i32x4;
typedef __attribute__((ext_vector_type(8))) short bf16x8;
typedef __attribute__((ext_vector_type(4))) float f32x4;

#define AS1 __attribute__((address_space(1)))
#define AS3 __attribute__((address_space(3)))

static __device__ __forceinline__ void glds16(const void* g, void* l) {
  __builtin_amdgcn_global_load_lds((const AS1 uint32_t*)g, (AS3 uint32_t*)l, 16, 0, 0);
}

static __device__ __forceinline__ uint32_t bf16pack_rn(float hi, float lo) {
  uint32_t h = __float_as_uint(hi) + 0x8000u;
  uint32_t l = __float_as_uint(lo) + 0x8000u;
  return __builtin_amdgcn_perm(h, l, 0x07060302u);
}

static __device__ __forceinline__ uint32_t pack4i8(int b0, int b1, int b2, int b3) {
  return ((uint32_t)b0 & 255u) | (((uint32_t)b1 & 255u) << 8) |
         (((uint32_t)b2 & 255u) << 16) | (((uint32_t)b3 & 255u) << 24);
}

// ---------- Kernel 1: A fp32 -> i8 per-row quant, ONE WAVE PER ROW ----------
// Zero barriers (round-8 version had 8 block-wide barriers). Row data stays
// register-resident (16 float4 = 64 VGPR) between max-pass and quant-pass.
__global__ void __launch_bounds__(256) a_quant(const float* __restrict__ A,
                                               int8_t* __restrict__ Ai,
                                               float* __restrict__ ascale) {
  const int t    = threadIdx.x;
  const int lane = t & 63;
  const int row  = blockIdx.x * 4 + (t >> 6);
  const float* src = A + (size_t)row * GK;
  float4 v[16];
  float m = 0.f;
  #pragma unroll
  for (int i = 0; i < 16; ++i) {
    v[i] = *(const float4*)(src + i * 256 + lane * 4);
    m = fmaxf(m, fmaxf(fmaxf(fabsf(v[i].x), fabsf(v[i].y)),
                       fmaxf(fabsf(v[i].z), fabsf(v[i].w))));
  }
  #pragma unroll
  for (int off = 32; off >= 1; off >>= 1)
    m = fmaxf(m, __shfl_xor(m, off, 64));
  const float rmax = fmaxf(m, 1e-20f);
  const float inv  = 127.0f / rmax;
  #pragma unroll
  for (int i = 0; i < 16; ++i) {
    uint32_t b = pack4i8((int)__builtin_rintf(v[i].x * inv),
                         (int)__builtin_rintf(v[i].y * inv),
                         (int)__builtin_rintf(v[i].z * inv),
                         (int)__builtin_rintf(v[i].w * inv));
    *(uint32_t*)(Ai + (size_t)row * GK + i * 256 + lane * 4) = b;
  }
  if (lane == 0) ascale[row] = rmax * (1.0f / 127.0f);
}

// ---------- Kernel 1b: per-column weight scale = 8*max_g s / 127 ----------
__global__ void __launch_bounds__(256) w_scale(const float* __restrict__ S,
                                               float* __restrict__ wscale,
                                               float* __restrict__ winv) {
  const int n = blockIdx.x * 256 + threadIdx.x;
  float m = 0.f;
  #pragma unroll 8
  for (int g = 0; g < 32; ++g) m = fmaxf(m, S[(size_t)g * GN + n]);
  wscale[n] = m * (8.0f / 127.0f);
  winv[n]   = 127.0f / (8.0f * m);
}

// ---------- Kernel 2: int4 -> i8 W^T [N][K], coalesced + LDS transpose ----------
// Tile 128k x 128n. Each Q word read exactly ONCE by one thread (round-8
// version re-read 8x, scattered 32KB apart). Thread (w=tid&15, kb=tid>>4)
// handles 8 words = 4 consecutive k x 8 n -> packs per-n uint32 (4 k-bytes),
// writes T32[n][kword ^ 4*(w&7)] (2-way LDS writes = free), reads out
// uint4 rows, writes Wt in 128-B contiguous segments.
__global__ void __launch_bounds__(256) w_quant(const float* __restrict__ S,
                                               const uint32_t* __restrict__ Q,
                                               const float* __restrict__ winv,
                                               int8_t* __restrict__ Wt) {
  __shared__ uint32_t T32[128 * 32];             // 16 KB
  const int tid = threadIdx.x;
  const int n0  = blockIdx.x * 128;
  const int k0  = blockIdx.y * 128;
  const int g   = blockIdx.y;                    // k0/128 = scale group
  const int w   = tid & 15;
  const int kb  = tid >> 4;                      // 0..15

  float r[8], c[8];
  {
    const float* sp = S + (size_t)g * GN + n0 + w * 8;
    const float* ip = winv + n0 + w * 8;
    float4 sa = *(const float4*)sp, sb = *(const float4*)(sp + 4);
    float4 ia = *(const float4*)ip, ib = *(const float4*)(ip + 4);
    const float sv[8] = {sa.x, sa.y, sa.z, sa.w, sb.x, sb.y, sb.z, sb.w};
    const float iv[8] = {ia.x, ia.y, ia.z, ia.w, ib.x, ib.y, ib.z, ib.w};
    #pragma unroll
    for (int j = 0; j < 8; ++j) { r[j] = sv[j] * iv[j]; c[j] = -8.0f * r[j]; }
  }

  const int swz = 4 * (w & 7);
  #pragma unroll
  for (int c2 = 0; c2 < 2; ++c2) {
    uint32_t q[4];
    #pragma unroll
    for (int i = 0; i < 4; ++i)
      q[i] = Q[(size_t)(k0 + c2 * 64 + kb * 4 + i) * QW + (n0 >> 3) + w];
    const int kword = c2 * 16 + kb;
    #pragma unroll
    for (int j = 0; j < 8; ++j) {
      int b[4];
      #pragma unroll
      for (int i = 0; i < 4; ++i) {
        float nib = (float)((q[i] >> (4 * j)) & 0xFu);
        b[i] = (int)__builtin_rintf(fmaf(nib, r[j], c[j]));
      }
      T32[(w * 8 + j) * 32 + (kword ^ swz)] = pack4i8(b[0], b[1], b[2], b[3]);
    }
  }
  __syncthreads();
  #pragma unroll
  for (int p = 0; p < 4; ++p) {
    int idx = p * 256 + tid;
    int n = idx >> 3, gr = idx & 7;
    uint4 v = *(const uint4*)(&T32[n * 32 + (gr ^ ((n >> 3) & 7)) * 4]);
    *(uint4*)(Wt + (size_t)(n0 + n) * GK + k0 + gr * 16) = v;
  }
}

// ---------- Kernel 3: i8 GEMM, K128 tiles, 128-B LDS rows ----------
// 128x128 block, 4 waves 2x2 (64x64), mfma_i32_16x16x64_i8. LDS row = 128 i8
// = one full 128-B line (restores the round-4/5 verified zero-conflict
// geometry: chunk_phys = chunk ^ (row&7), swizzle on the glds SOURCE addr).
// K128 halves the barrier count vs round 8 (32 steps instead of 64).
// 32 KB LDS/block x 4 blocks = 128 KB <= 160 KB; VGPR+AGPR <= 128 -> 4 blk/CU.
__global__ void __launch_bounds__(256, 4) gemm_i8(const int8_t* __restrict__ Ai,
                                                  const int8_t* __restrict__ Wi,
                                                  const float* __restrict__ ascale,
                                                  const float* __restrict__ wscale,
                                                  float* __restrict__ C) {
  __shared__ __align__(16) int8_t As[128 * 128];  // 16 KB
  __shared__ __align__(16) int8_t Bs[128 * 128];  // 16 KB

  const int tid  = threadIdx.x;
  const int m0   = blockIdx.y * 128;
  const int n0   = blockIdx.x * 128;
  const int ln   = tid & 63;
  const int wid  = tid >> 6;
  const int wm   = (wid >> 1) * 64;
  const int wn   = (wid & 1) * 64;
  const int col  = ln & 15;
  const int quad = ln >> 4;

  // staging: thread t, pass c -> LDS line r = c*32 + (t>>3), phys chunk h=t&7;
  // slot holds logical chunk h ^ (r&7); (c*32)&7==0 so source offset is c-invariant
  const int rs = tid >> 3;                            // 0..31
  const int qo = ((tid & 7) ^ (rs & 7)) * 16;         // swizzled source chunk
  const int8_t* Asrc = Ai + (size_t)(m0 + rs) * GK + qo;
  const int8_t* Bsrc = Wi + (size_t)(n0 + rs) * GK + qo;

  // fragment reads: row = base16 + col -> row&7 = col&7
  const int sw = col & 7;

  i32x4 acc[4][4];
  #pragma unroll
  for (int i = 0; i < 4; ++i)
    #pragma unroll
    for (int j = 0; j < 4; ++j)
      acc[i][j] = (i32x4){0, 0, 0, 0};

  for (int k0 = 0; k0 < GK; k0 += 128) {
    #pragma unroll
    for (int c = 0; c < 4; ++c) {
      glds16(Asrc + (size_t)c * 32 * GK + k0, &As[(c * 256 + tid) * 16]);
      glds16(Bsrc + (size_t)c * 32 * GK + k0, &Bs[(c * 256 + tid) * 16]);
    }

    __syncthreads();   // drains vmcnt; tiles ready

    #pragma unroll
    for (int kk = 0; kk < 2; ++kk) {
      const int cq = ((kk * 4 + quad) ^ sw) * 16;     // phys chunk offset
      i32x4 af[4], bfr[4];
      #pragma unroll
      for (int t = 0; t < 4; ++t) {
        af[t]  = *(const i32x4*)(&As[(wm + t * 16 + col) * 128 + cq]);
        bfr[t] = *(const i32x4*)(&Bs[(wn + t * 16 + col) * 128 + cq]);
      }
      #pragma unroll
      for (int mt = 0; mt < 4; ++mt)
        #pragma unroll
        for (int nt = 0; nt < 4; ++nt)
          acc[mt][nt] = __builtin_amdgcn_mfma_i32_16x16x64_i8(
                            af[mt], bfr[nt], acc[mt][nt], 0, 0, 0);
    }

    __syncthreads();   // reads done before next stage overwrites
  }

  // epilogue: C/D col=lane&15, row=quad*4+reg (dtype-independent, m121-128)
  #pragma unroll
  for (int mt = 0; mt < 4; ++mt) {
    float4 a4 = *(const float4*)(ascale + m0 + wm + mt * 16 + quad * 4);
    const float ar[4] = {a4.x, a4.y, a4.z, a4.w};
    #pragma unroll
    for (int nt = 0; nt < 4; ++nt) {
      const float ws = wscale[n0 + wn + nt * 16 + col];
      #pragma unroll
      for (int r = 0; r < 4; ++r)
        C[(size_t)(m0 + wm + mt * 16 + quad * 4 + r) * GN
          + n0 + wn + nt * 16 + col] = (float)acc[mt][nt][r] * (ar[r] * ws);
    }
  }
}

// ---------------- Fallback: fused dequant GEMM (round-2 kernel) ----------------
#define BM 128
#define BN 128
#define BK 32

__global__ void __launch_bounds__(256) w4a32_gemm(
    const float* __restrict__ A,
    const float* __restrict__ S,
    const uint32_t* __restrict__ Q,
    float* __restrict__ C)
{
  __shared__ __align__(16) ushort As[BM*BK];
  __shared__ __align__(16) ushort Bs[BN*BK];

  const int tid  = threadIdx.x;
  const int m0   = blockIdx.y*BM;
  const int n0   = blockIdx.x*BN;
  const int wcol  = tid & 15;
  const int kpair = tid >> 4;
  const int ln   = tid & 63;
  const int wid  = tid >> 6;
  const int wm   = (wid >> 1) * 64;
  const int wn   = (wid & 1) * 64;
  const int col  = ln & 15;
  const int quad = ln >> 4;

  f32x4 acc[4][4];
  #pragma unroll
  for (int i=0;i<4;++i)
    #pragma unroll
    for (int j=0;j<4;++j)
      acc[i][j] = (f32x4){0.f,0.f,0.f,0.f};

  float sv[8], cv[8];
  float4 spf0, spf1;

  const float*    Abase = A + (size_t)m0 * GK;
  const uint32_t* Qbase = Q + (size_t)(n0>>3) + wcol;

  {
    const float* sp = S + n0 + wcol*8;
    spf0 = *(const float4*)sp;
    spf1 = *(const float4*)(sp + 4);
  }

  float4 a4[4];
  uint32_t wqa, wqb;
  #pragma unroll
  for (int i=0;i<4;++i) {
    int f = tid + i*256;
    a4[i] = *(const float4*)(Abase + (size_t)(f>>3)*GK + ((f&7)*4));
  }
  wqa = Qbase[(size_t)(2*kpair)   * QW];
  wqb = Qbase[(size_t)(2*kpair+1) * QW];

  for (int k0 = 0; k0 < GK; k0 += BK) {
    if ((k0 & 127) == 0) {
      sv[0]=spf0.x; sv[1]=spf0.y; sv[2]=spf0.z; sv[3]=spf0.w;
      sv[4]=spf1.x; sv[5]=spf1.y; sv[6]=spf1.z; sv[7]=spf1.w;
      #pragma unroll
      for (int j=0;j<8;++j) cv[j] = -8.0f * sv[j];
    }

    #pragma unroll
    for (int i=0;i<4;++i) {
      int f = tid + i*256;
      int row = f>>3, c4 = f&7;
      *(uint2*)(&As[row*BK + c4*4]) =
        make_uint2(bf16pack_rn(a4[i].y, a4[i].x), bf16pack_rn(a4[i].w, a4[i].z));
    }

    {
      const int kk = (2*kpair) ^ (8*(wcol&3));
      #pragma unroll
      for (int j=0;j<8;++j) {
        float fa = (float)((wqa >> (4*j)) & 0xFu);
        float fb = (float)((wqb >> (4*j)) & 0xFu);
        float wa = fmaf(fa, sv[j], cv[j]);
        float wb = fmaf(fb, sv[j], cv[j]);
        int n = wcol*8 + j;
        *(uint32_t*)(&Bs[n*BK + kk]) = bf16pack_rn(wb, wa);
      }
    }

    int kn = k0 + BK; if (kn >= GK) kn = 0;
    if ((kn & 127) == 0) {
      const float* sp = S + (size_t)(kn>>7)*GN + n0 + wcol*8;
      spf0 = *(const float4*)sp;
      spf1 = *(const float4*)(sp + 4);
    }
    #pragma unroll
    for (int i=0;i<4;++i) {
      int f = tid + i*256;
      a4[i] = *(const float4*)(Abase + (size_t)(f>>3)*GK + kn + ((f&7)*4));
    }
    wqa = Qbase[(size_t)(kn + 2*kpair)   * QW];
    wqb = Qbase[(size_t)(kn + 2*kpair+1) * QW];

    __syncthreads();

    bf16x8 af[4], bfr[4];
    #pragma unroll
    for (int t=0;t<4;++t) {
      af[t] = *(const bf16x8*)(&As[(wm + t*16 + col)*BK + quad*8]);
      int n = wn + t*16 + col;
      int kk = (quad*8) ^ (8*((n>>3)&3));
      bfr[t] = *(const bf16x8*)(&Bs[n*BK + kk]);
    }
    #pragma unroll
    for (int mt=0;mt<4;++mt)
      #pragma unroll
      for (int nt=0;nt<4;++nt)
        acc[mt][nt] = __builtin_amdgcn_mfma_f32_16x16x32_bf16(
                          af[mt], bfr[nt], acc[mt][nt], 0, 0, 0);

    __syncthreads();
  }

  #pragma unroll
  for (int mt=0;mt<4;++mt)
    #pragma unroll
    for (int nt=0;nt<4;++nt)
      #pragma unroll
      for (int r=0;r<4;++r)
        C[(size_t)(m0 + wm + mt*16 + quad*4 + r)*GN + n0 + wn + nt*16 + col]
          = acc[mt][nt][r];
}

extern "C" void kernel_launch(void* const* d_in, const int* in_sizes, int n_in,
                              void* d_out, int out_size, void* d_ws, size_t ws_size,
                              hipStream_t stream) {
  const float*    A = (const float*)d_in[0];
  const float*    S = (const float*)d_in[1];
  const uint32_t* Q = (const uint32_t*)d_in[2];
  float*          C = (float*)d_out;

  const size_t need = (size_t)GM * GK + (size_t)GN * GK + 3 * 4096 * 4 + 4096;
  if (ws_size >= need) {
    int8_t* Ai  = (int8_t*)d_ws;                          // [M][K] i8, 16 MB
    int8_t* Wt  = Ai + (size_t)GM * GK;                   // [N][K] i8, 16 MB
    float* ascale = (float*)(Wt + (size_t)GN * GK);       // 4096 f32
    float* wscale = ascale + 4096;
    float* winv   = wscale + 4096;
    a_quant<<<dim3(GM / 4), dim3(256), 0, stream>>>(A, Ai, ascale);
    w_scale<<<dim3(GN / 256), dim3(256), 0, stream>>>(S, wscale, winv);
    w_quant<<<dim3(GN / 128, GK / 128), dim3(256), 0, stream>>>(S, Q, winv, Wt);
    gemm_i8<<<dim3(GN / 128, GM / 128), dim3(256), 0, stream>>>(Ai, Wt, ascale, wscale, C);
  } else {
    w4a32_gemm<<<dim3(GN / BN, GM / BM), dim3(256), 0, stream>>>(A, S, Q, C);
  }
}